// Round 5
// baseline (971.050 us; speedup 1.0000x reference)
//
#include <hip/hip_runtime.h>
#include <hip/hip_bf16.h>

// 3-layer GCN: per layer  out = relu(dinv .* segsum(dinv .* (X@W)) + b)
// fp16 message pipeline: GEMMs via mfma_f32_16x16x32_f16 (f32 accum).
// CSR build = two-level counting sort: coarse bucket bin (sequential cursor
// writes -> no 16x line amplification) + per-bucket LDS counting sort that
// emits eidx/rowptr/dinv with fully coalesced writes.

#define NNODES 100000
#define NB 391          // buckets of 256 nodes: ceil(100000/256)
#define BCAP 12288      // per-bucket LDS scatter capacity (mean 4096, sd ~64)

typedef _Float16 half8  __attribute__((ext_vector_type(8)));
typedef _Float16 half4v __attribute__((ext_vector_type(4)));
typedef _Float16 half2v __attribute__((ext_vector_type(2)));
typedef float    floatx4 __attribute__((ext_vector_type(4)));

static __device__ __forceinline__ floatx4 h2f4(half4v v) {
    return (floatx4){(float)v.x, (float)v.y, (float)v.z, (float)v.w};
}

// ---------------- CSR build ----------------
__global__ __launch_bounds__(256) void zero_small_k(int* __restrict__ p, int n) {
    int i = blockIdx.x * 256 + threadIdx.x;
    if (i < n) p[i] = 0;
}

// bucket histogram: LDS-staged, few global atomics
__global__ __launch_bounds__(256) void hist_k(const int* __restrict__ dst,
                                              int* __restrict__ bcnt, int e) {
    __shared__ int h[NB];
    for (int q = threadIdx.x; q < NB; q += 256) h[q] = 0;
    __syncthreads();
    int e4 = e >> 2;
    int stride = gridDim.x * 256;
    for (int i = blockIdx.x * 256 + threadIdx.x; i < e4; i += stride) {
        int4 d = ((const int4*)dst)[i];
        atomicAdd(&h[d.x >> 8], 1);
        atomicAdd(&h[d.y >> 8], 1);
        atomicAdd(&h[d.z >> 8], 1);
        atomicAdd(&h[d.w >> 8], 1);
    }
    if (blockIdx.x == 0 && threadIdx.x == 0) {
        for (int i = e4 * 4; i < e; ++i) atomicAdd(&bcnt[dst[i] >> 8], 1);
    }
    __syncthreads();
    for (int q = threadIdx.x; q < NB; q += 256) {
        int v = h[q];
        if (v) atomicAdd(&bcnt[q], v);
    }
}

// exclusive scan of bucket counts -> bbase, init bcur
__global__ __launch_bounds__(512) void scan_buckets_k(const int* __restrict__ bcnt,
                                                      int* __restrict__ bbase,
                                                      int* __restrict__ bcur, int e) {
    __shared__ int lds[512];
    int t = threadIdx.x;
    int v = (t < NB) ? bcnt[t] : 0;
    lds[t] = v;
    __syncthreads();
    #pragma unroll
    for (int off = 1; off < 512; off <<= 1) {
        int u = (t >= off) ? lds[t - off] : 0;
        __syncthreads();
        lds[t] += u;
        __syncthreads();
    }
    int excl = lds[t] - v;
    if (t < NB) { bbase[t] = excl; bcur[t] = excl; }
    if (t == 0) bbase[NB] = e;
}

// bin pass: sequential-cursor writes per bucket (lines fill before eviction)
__global__ __launch_bounds__(256) void bin_k(const int* __restrict__ src,
                                             const int* __restrict__ dst,
                                             int* __restrict__ bcur,
                                             unsigned* __restrict__ binned, int e) {
    int base = (blockIdx.x * 256 + threadIdx.x) * 4;
    if (base + 4 <= e) {
        int4 d = *(const int4*)(dst + base);
        int4 s = *(const int4*)(src + base);
        int p0 = atomicAdd(&bcur[d.x >> 8], 1);
        int p1 = atomicAdd(&bcur[d.y >> 8], 1);
        int p2 = atomicAdd(&bcur[d.z >> 8], 1);
        int p3 = atomicAdd(&bcur[d.w >> 8], 1);
        binned[p0] = ((unsigned)(d.x & 255) << 17) | (unsigned)s.x;
        binned[p1] = ((unsigned)(d.y & 255) << 17) | (unsigned)s.y;
        binned[p2] = ((unsigned)(d.z & 255) << 17) | (unsigned)s.z;
        binned[p3] = ((unsigned)(d.w & 255) << 17) | (unsigned)s.w;
    } else {
        for (int i = base; i < e; ++i) {
            int p = atomicAdd(&bcur[dst[i] >> 8], 1);
            binned[p] = ((unsigned)(dst[i] & 255) << 17) | (unsigned)src[i];
        }
    }
}

// per-bucket exact counting sort in LDS; emits eidx (coalesced), rowptr, dinv
__global__ __launch_bounds__(256) void bucket_fill_k(
    const unsigned* __restrict__ binned, const int* __restrict__ bbase,
    int* __restrict__ rowptr, int* __restrict__ eidx,
    float* __restrict__ dinv, int n, int e) {
    __shared__ int cnt[256];
    __shared__ int cur[256];
    __shared__ int lds[256];
    __shared__ int sbuf[BCAP];
    int b = blockIdx.x, t = threadIdx.x;
    int beg = bbase[b], end = bbase[b + 1];
    int m = end - beg;
    cnt[t] = 0;
    __syncthreads();
    for (int q = t; q < m; q += 256) {
        unsigned r = binned[beg + q];
        atomicAdd(&cnt[r >> 17], 1);
    }
    __syncthreads();
    int v = cnt[t];
    lds[t] = v;
    __syncthreads();
    #pragma unroll
    for (int off = 1; off < 256; off <<= 1) {
        int u = (t >= off) ? lds[t - off] : 0;
        __syncthreads();
        lds[t] += u;
        __syncthreads();
    }
    int excl = lds[t] - v;
    int node = b * 256 + t;
    if (node < n) {
        rowptr[node] = beg + excl;
        dinv[node] = rsqrtf(1.0f + (float)v);
    }
    if (b == NB - 1 && t == 0) rowptr[n] = e;
    cur[t] = excl;
    __syncthreads();
    for (int q = t; q < m; q += 256) {
        unsigned r = binned[beg + q];
        int p = atomicAdd(&cur[r >> 17], 1);
        if (p < BCAP) sbuf[p] = (int)(r & 0x1FFFFu);
    }
    __syncthreads();
    for (int q = t; q < m; q += 256) eidx[beg + q] = sbuf[q];
}

// ---------------- MFMA GEMM: G(fp16) = (X @ W) * dinv[row] ----------------
template<typename TA, int FIN, int FOUT>
__global__ __launch_bounds__(256) void gemm_mfma_k(
    const TA* __restrict__ X, const float* __restrict__ W,
    const float* __restrict__ dinv, _Float16* __restrict__ G, int n)
{
    constexpr int KC = (FIN > 128) ? 128 : FIN;
    constexpr int KP = KC + 8;
    constexpr int NT = FOUT / 16;
    __shared__ _Float16 wT[FOUT * KP];   // wT[n][k] = W[k][n]

    const int tid  = threadIdx.x;
    const int wave = tid >> 6;
    const int lane = tid & 63;
    const int mrow = lane & 15;
    const int kq   = (lane >> 4) * 8;

    const int m0 = blockIdx.x * 128 + wave * 32;
    int r0 = m0 + mrow;      if (r0 > n - 1) r0 = n - 1;
    int r1 = m0 + 16 + mrow; if (r1 > n - 1) r1 = n - 1;

    floatx4 acc[2][NT];
    #pragma unroll
    for (int i = 0; i < 2; ++i)
        #pragma unroll
        for (int j = 0; j < NT; ++j) acc[i][j] = (floatx4){0.f, 0.f, 0.f, 0.f};

    for (int kc = 0; kc < FIN; kc += KC) {
        if (kc) __syncthreads();
        for (int q = tid; q < KC * FOUT; q += 256) {
            int k = q / FOUT, nn = q % FOUT;
            wT[nn * KP + k] = (_Float16)W[(size_t)(kc + k) * FOUT + nn];
        }
        __syncthreads();

        #pragma unroll
        for (int kk = 0; kk < KC; kk += 32) {
            half8 a0, a1;
            if constexpr (sizeof(TA) == 2) {
                const _Float16* xp = (const _Float16*)X;
                a0 = *(const half8*)(xp + (size_t)r0 * FIN + kc + kk + kq);
                a1 = *(const half8*)(xp + (size_t)r1 * FIN + kc + kk + kq);
            } else {
                const float* xp0 = (const float*)X + (size_t)r0 * FIN + kc + kk + kq;
                const float* xp1 = (const float*)X + (size_t)r1 * FIN + kc + kk + kq;
                float4 u0 = *(const float4*)xp0, u1 = *(const float4*)(xp0 + 4);
                float4 v0 = *(const float4*)xp1, v1 = *(const float4*)(xp1 + 4);
                a0 = (half8){(_Float16)u0.x, (_Float16)u0.y, (_Float16)u0.z, (_Float16)u0.w,
                             (_Float16)u1.x, (_Float16)u1.y, (_Float16)u1.z, (_Float16)u1.w};
                a1 = (half8){(_Float16)v0.x, (_Float16)v0.y, (_Float16)v0.z, (_Float16)v0.w,
                             (_Float16)v1.x, (_Float16)v1.y, (_Float16)v1.z, (_Float16)v1.w};
            }
            #pragma unroll
            for (int ct = 0; ct < NT; ++ct) {
                half8 b = *(const half8*)&wT[(ct * 16 + mrow) * KP + kk + kq];
                acc[0][ct] = __builtin_amdgcn_mfma_f32_16x16x32_f16(a0, b, acc[0][ct], 0, 0, 0);
                acc[1][ct] = __builtin_amdgcn_mfma_f32_16x16x32_f16(a1, b, acc[1][ct], 0, 0, 0);
            }
        }
    }

    #pragma unroll
    for (int rt = 0; rt < 2; ++rt) {
        #pragma unroll
        for (int reg = 0; reg < 4; ++reg) {
            int r = m0 + rt * 16 + (lane >> 4) * 4 + reg;
            if (r < n) {
                float s = dinv[r];
                #pragma unroll
                for (int ct = 0; ct < NT; ++ct) {
                    G[(size_t)r * FOUT + ct * 16 + mrow] = (_Float16)(acc[rt][ct][reg] * s);
                }
            }
        }
    }
}

// -------- CSR gather segsum, F=128: half-wave, 4 rows in flight per half --------
template<bool RELU, typename OutT>
__global__ __launch_bounds__(256) void gather128_k(
    const _Float16* __restrict__ g, const int* __restrict__ rowptr,
    const int* __restrict__ eidx, const float* __restrict__ dinv,
    const float* __restrict__ bias, OutT* __restrict__ out, int n)
{
    int wave = threadIdx.x >> 6;
    int lane = threadIdx.x & 63;
    int half = lane >> 5;
    int hl   = lane & 31;
    int node = blockIdx.x * 4 + wave;
    if (node >= n) return;

    int beg = rowptr[node];
    int end = rowptr[node + 1];

    const half4v* g4 = (const half4v*)g;     // row stride = 32 half4
    floatx4 aA = {0.f,0.f,0.f,0.f}, aB = aA, aC = aA, aD = aA;
    if (half == 0) aA = h2f4(g4[(size_t)node * 32 + hl]);   // self loop

    for (int j0 = beg; j0 < end; j0 += 64) {
        int m = end - j0; if (m > 64) m = 64;
        int id = (lane < m) ? eidx[j0 + lane] : 0;
        int t = 0;
        for (; t + 7 < m; t += 8) {
            int i0 = __shfl(id, t + half);
            int i1 = __shfl(id, t + 2 + half);
            int i2 = __shfl(id, t + 4 + half);
            int i3 = __shfl(id, t + 6 + half);
            half4v v0 = g4[(size_t)i0 * 32 + hl];
            half4v v1 = g4[(size_t)i1 * 32 + hl];
            half4v v2 = g4[(size_t)i2 * 32 + hl];
            half4v v3 = g4[(size_t)i3 * 32 + hl];
            aA += h2f4(v0); aB += h2f4(v1); aC += h2f4(v2); aD += h2f4(v3);
        }
        for (; t + 1 < m; t += 2) {
            int i0 = __shfl(id, t + half);
            aA += h2f4(g4[(size_t)i0 * 32 + hl]);
        }
        if (t < m) {
            int i0 = __shfl(id, t);
            if (half == 0) aA += h2f4(g4[(size_t)i0 * 32 + hl]);
        }
    }
    aA += aB; aC += aD; aA += aC;
    aA.x += __shfl_down(aA.x, 32);
    aA.y += __shfl_down(aA.y, 32);
    aA.z += __shfl_down(aA.z, 32);
    aA.w += __shfl_down(aA.w, 32);

    if (half == 0) {
        float sc = dinv[node];
        float4 bb = *(const float4*)(bias + 4 * hl);
        float o0 = fmaf(aA.x, sc, bb.x);
        float o1 = fmaf(aA.y, sc, bb.y);
        float o2 = fmaf(aA.z, sc, bb.z);
        float o3 = fmaf(aA.w, sc, bb.w);
        if (RELU) {
            o0 = fmaxf(o0, 0.f); o1 = fmaxf(o1, 0.f);
            o2 = fmaxf(o2, 0.f); o3 = fmaxf(o3, 0.f);
        }
        if constexpr (sizeof(OutT) == 2) {
            ((half4v*)out)[(size_t)node * 32 + hl] =
                (half4v){(_Float16)o0, (_Float16)o1, (_Float16)o2, (_Float16)o3};
        } else {
            *(float4*)((float*)out + (size_t)node * 128 + 4 * hl) =
                make_float4(o0, o1, o2, o3);
        }
    }
}

// -------- F=64 variant: half-wave, half2 loads, 4 rows in flight per half --------
template<bool RELU>
__global__ __launch_bounds__(256) void gather64_k(
    const _Float16* __restrict__ g, const int* __restrict__ rowptr,
    const int* __restrict__ eidx, const float* __restrict__ dinv,
    const float* __restrict__ bias, float* __restrict__ out, int n)
{
    int wave = threadIdx.x >> 6;
    int lane = threadIdx.x & 63;
    int half = lane >> 5;
    int hl   = lane & 31;
    int node = blockIdx.x * 4 + wave;
    if (node >= n) return;

    int beg = rowptr[node];
    int end = rowptr[node + 1];

    const half2v* g2 = (const half2v*)g;     // row stride = 32 half2
    float ax=0.f, ay=0.f, bx=0.f, by=0.f, cx=0.f, cy=0.f, dx=0.f, dy=0.f;
    if (half == 0) {
        half2v v = g2[(size_t)node * 32 + hl];
        ax = (float)v.x; ay = (float)v.y;
    }

    for (int j0 = beg; j0 < end; j0 += 64) {
        int m = end - j0; if (m > 64) m = 64;
        int id = (lane < m) ? eidx[j0 + lane] : 0;
        int t = 0;
        for (; t + 7 < m; t += 8) {
            int i0 = __shfl(id, t + half);
            int i1 = __shfl(id, t + 2 + half);
            int i2 = __shfl(id, t + 4 + half);
            int i3 = __shfl(id, t + 6 + half);
            half2v v0 = g2[(size_t)i0 * 32 + hl];
            half2v v1 = g2[(size_t)i1 * 32 + hl];
            half2v v2 = g2[(size_t)i2 * 32 + hl];
            half2v v3 = g2[(size_t)i3 * 32 + hl];
            ax += (float)v0.x; ay += (float)v0.y;
            bx += (float)v1.x; by += (float)v1.y;
            cx += (float)v2.x; cy += (float)v2.y;
            dx += (float)v3.x; dy += (float)v3.y;
        }
        for (; t + 1 < m; t += 2) {
            int i0 = __shfl(id, t + half);
            half2v v0 = g2[(size_t)i0 * 32 + hl];
            ax += (float)v0.x; ay += (float)v0.y;
        }
        if (t < m) {
            int i0 = __shfl(id, t);
            if (half == 0) {
                half2v v0 = g2[(size_t)i0 * 32 + hl];
                ax += (float)v0.x; ay += (float)v0.y;
            }
        }
    }
    ax += bx + cx + dx; ay += by + cy + dy;
    ax += __shfl_down(ax, 32);
    ay += __shfl_down(ay, 32);

    if (half == 0) {
        float sc = dinv[node];
        float2 bb = *(const float2*)(bias + 2 * hl);
        float ox = fmaf(ax, sc, bb.x);
        float oy = fmaf(ay, sc, bb.y);
        if (RELU) { ox = fmaxf(ox, 0.f); oy = fmaxf(oy, 0.f); }
        *(float2*)(out + (size_t)node * 64 + 2 * hl) = make_float2(ox, oy);
    }
}

extern "C" void kernel_launch(void* const* d_in, const int* in_sizes, int n_in,
                              void* d_out, int out_size, void* d_ws, size_t ws_size,
                              hipStream_t stream) {
    const float* x  = (const float*)d_in[0];
    const int*   ei = (const int*)d_in[1];     // [2, E] int32
    const float* W1 = (const float*)d_in[2];
    const float* b1 = (const float*)d_in[3];
    const float* W2 = (const float*)d_in[4];
    const float* b2 = (const float*)d_in[5];
    const float* W3 = (const float*)d_in[6];
    const float* b3 = (const float*)d_in[7];
    float* out = (float*)d_out;

    const int N = NNODES;
    const int E = in_sizes[1] / 2;
    const int* srcI = ei;
    const int* dstI = ei + E;

    char* ws = (char*)d_ws;
    size_t p = 0;
    auto alloc = [&](size_t bytes) { void* r = ws + p; p = (p + bytes + 255) & ~(size_t)255; return r; };
    float*     dinv   = (float*)    alloc((size_t)N * 4);
    int*       rowptr = (int*)      alloc((size_t)(N + 1) * 4);
    int*       bcnt   = (int*)      alloc((size_t)(NB + 1) * 4);
    int*       bbase  = (int*)      alloc((size_t)(NB + 1) * 4);
    int*       bcur   = (int*)      alloc((size_t)(NB + 1) * 4);
    unsigned*  binned = (unsigned*) alloc((size_t)E * 4);
    int*       eidx   = (int*)      alloc((size_t)E * 4);
    _Float16*  A      = (_Float16*) alloc((size_t)N * 128 * 2);
    _Float16*  Ch     = (_Float16*) alloc((size_t)N * 128 * 2);

    const int nb_node4 = (N + 3) / 4;
    const int nb_gemm = (N + 127) / 128;
    const int nb_bin = (E + 1023) / 1024;

    // ---- CSR build: coarse bin + per-bucket LDS counting sort ----
    zero_small_k<<<2, 256, 0, stream>>>(bcnt, NB);
    hist_k<<<128, 256, 0, stream>>>(dstI, bcnt, E);
    scan_buckets_k<<<1, 512, 0, stream>>>(bcnt, bbase, bcur, E);
    bin_k<<<nb_bin, 256, 0, stream>>>(srcI, dstI, bcur, binned, E);
    bucket_fill_k<<<NB, 256, 0, stream>>>(binned, bbase, rowptr, eidx, dinv, N, E);

    // ---- layer 1: FEAT=256 -> HID=128 ----
    gemm_mfma_k<float, 256, 128><<<nb_gemm, 256, 0, stream>>>(x, W1, dinv, A, N);
    gather128_k<true, _Float16><<<nb_node4, 256, 0, stream>>>(A, rowptr, eidx, dinv, b1, Ch, N);

    // ---- layer 2: HID=128 -> HID=128 ----
    gemm_mfma_k<_Float16, 128, 128><<<nb_gemm, 256, 0, stream>>>(Ch, W2, dinv, A, N);
    gather128_k<true, _Float16><<<nb_node4, 256, 0, stream>>>(A, rowptr, eidx, dinv, b2, Ch, N);

    // ---- layer 3: HID=128 -> OUT=64 ----
    gemm_mfma_k<_Float16, 128, 64><<<nb_gemm, 256, 0, stream>>>(Ch, W3, dinv, A, N);
    gather64_k<false><<<nb_node4, 256, 0, stream>>>(A, rowptr, eidx, dinv, b3, out, N);
}

// Round 6
// 448.769 us; speedup vs baseline: 2.1638x; 2.1638x over previous
//
#include <hip/hip_runtime.h>
#include <hip/hip_bf16.h>

// 3-layer GCN: per layer  out = relu(dinv .* segsum(dinv .* (X@W)) + b)
// fp16 message pipeline: GEMMs via mfma_f32_16x16x32_f16 (f32 accum).
// CSR build = deterministic two-level counting sort with ZERO global atomics:
//   blockhist (per-block LDS hist) -> per-bucket scan -> rank+scatter (LDS
//   ranks) -> per-bucket LDS counting sort emitting eidx/rowptr/dinv.
// (r5 lesson: 391 shared global cursors serialized at ~350ns/atomic — never
//  funnel E atomics into few addresses.)

#define NNODES 100000
#define NB 391          // buckets of 256 nodes: ceil(100000/256)
#define PB 2048         // edges per partition block
#define BCAP 12288      // per-bucket LDS sort capacity (mean 4096, sd ~64)

typedef _Float16 half8  __attribute__((ext_vector_type(8)));
typedef _Float16 half4v __attribute__((ext_vector_type(4)));
typedef _Float16 half2v __attribute__((ext_vector_type(2)));
typedef float    floatx4 __attribute__((ext_vector_type(4)));

static __device__ __forceinline__ floatx4 h2f4(half4v v) {
    return (floatx4){(float)v.x, (float)v.y, (float)v.z, (float)v.w};
}

// ---------------- CSR build: deterministic partition ----------------
// pass A: per-block histogram over NB buckets, coalesced row write
__global__ __launch_bounds__(256) void blockhist_k(const int* __restrict__ dst,
                                                   int* __restrict__ H, int e) {
    __shared__ int h[NB];
    for (int q = threadIdx.x; q < NB; q += 256) h[q] = 0;
    __syncthreads();
    int base = blockIdx.x * PB;
    int lim = e - base; if (lim > PB) lim = PB;
    for (int i = threadIdx.x; i < lim; i += 256)
        atomicAdd(&h[dst[base + i] >> 8], 1);
    __syncthreads();
    for (int q = threadIdx.x; q < NB; q += 256)
        H[(size_t)blockIdx.x * NB + q] = h[q];
}

// pass B: per-bucket exclusive scan over blocks; emits O[block][b], T[b]
__global__ __launch_bounds__(256) void bucketscan_k(const int* __restrict__ H,
                                                    int* __restrict__ O,
                                                    int* __restrict__ T, int npb) {
    __shared__ int lds[256];
    int b = blockIdx.x, t = threadIdx.x;
    int running = 0;
    for (int c0 = 0; c0 < npb; c0 += 256) {
        int idx = c0 + t;
        int v = (idx < npb) ? H[(size_t)idx * NB + b] : 0;
        lds[t] = v;
        __syncthreads();
        #pragma unroll
        for (int off = 1; off < 256; off <<= 1) {
            int u = (t >= off) ? lds[t - off] : 0;
            __syncthreads();
            lds[t] += u;
            __syncthreads();
        }
        int excl = lds[t] - v + running;
        if (idx < npb) O[(size_t)idx * NB + b] = excl;
        running += lds[255];
        __syncthreads();
    }
    if (t == 0) T[b] = running;
}

// tiny: exclusive scan of T -> bbase; bbase[NB] = e
__global__ __launch_bounds__(512) void scanT_k(const int* __restrict__ T,
                                               int* __restrict__ bbase, int e) {
    __shared__ int lds[512];
    int t = threadIdx.x;
    int v = (t < NB) ? T[t] : 0;
    lds[t] = v;
    __syncthreads();
    #pragma unroll
    for (int off = 1; off < 512; off <<= 1) {
        int u = (t >= off) ? lds[t - off] : 0;
        __syncthreads();
        lds[t] += u;
        __syncthreads();
    }
    if (t < NB) bbase[t] = lds[t] - v;
    if (t == 0) bbase[NB] = e;
}

// pass C: LDS ranks (uncontended) + scatter to exact deterministic offsets
__global__ __launch_bounds__(256) void scatter_k(const int* __restrict__ src,
                                                 const int* __restrict__ dst,
                                                 const int* __restrict__ O,
                                                 const int* __restrict__ bbase,
                                                 unsigned* __restrict__ binned, int e) {
    __shared__ int cur[NB];
    for (int q = threadIdx.x; q < NB; q += 256)
        cur[q] = bbase[q] + O[(size_t)blockIdx.x * NB + q];
    __syncthreads();
    int base = blockIdx.x * PB;
    int lim = e - base; if (lim > PB) lim = PB;
    for (int i = threadIdx.x; i < lim; i += 256) {
        int d = dst[base + i];
        int s = src[base + i];
        int p = atomicAdd(&cur[d >> 8], 1);
        binned[p] = ((unsigned)(d & 255) << 17) | (unsigned)s;
    }
}

// per-bucket exact counting sort in LDS; emits eidx (coalesced), rowptr, dinv
__global__ __launch_bounds__(256) void bucket_fill_k(
    const unsigned* __restrict__ binned, const int* __restrict__ bbase,
    int* __restrict__ rowptr, int* __restrict__ eidx,
    float* __restrict__ dinv, int n, int e) {
    __shared__ int cnt[256];
    __shared__ int cur[256];
    __shared__ int lds[256];
    __shared__ int sbuf[BCAP];
    int b = blockIdx.x, t = threadIdx.x;
    int beg = bbase[b], end = bbase[b + 1];
    int m = end - beg;
    cnt[t] = 0;
    __syncthreads();
    for (int q = t; q < m; q += 256) {
        unsigned r = binned[beg + q];
        atomicAdd(&cnt[r >> 17], 1);
    }
    __syncthreads();
    int v = cnt[t];
    lds[t] = v;
    __syncthreads();
    #pragma unroll
    for (int off = 1; off < 256; off <<= 1) {
        int u = (t >= off) ? lds[t - off] : 0;
        __syncthreads();
        lds[t] += u;
        __syncthreads();
    }
    int excl = lds[t] - v;
    int node = b * 256 + t;
    if (node < n) {
        rowptr[node] = beg + excl;
        dinv[node] = rsqrtf(1.0f + (float)v);
    }
    if (b == NB - 1 && t == 0) rowptr[n] = e;
    cur[t] = excl;
    __syncthreads();
    for (int q = t; q < m; q += 256) {
        unsigned r = binned[beg + q];
        int p = atomicAdd(&cur[r >> 17], 1);
        if (p < BCAP) sbuf[p] = (int)(r & 0x1FFFFu);
    }
    __syncthreads();
    for (int q = t; q < m; q += 256) eidx[beg + q] = sbuf[q];
}

// ---------------- MFMA GEMM: G(fp16) = (X @ W) * dinv[row] ----------------
template<typename TA, int FIN, int FOUT>
__global__ __launch_bounds__(256) void gemm_mfma_k(
    const TA* __restrict__ X, const float* __restrict__ W,
    const float* __restrict__ dinv, _Float16* __restrict__ G, int n)
{
    constexpr int KC = (FIN > 128) ? 128 : FIN;
    constexpr int KP = KC + 8;
    constexpr int NT = FOUT / 16;
    __shared__ _Float16 wT[FOUT * KP];   // wT[n][k] = W[k][n]

    const int tid  = threadIdx.x;
    const int wave = tid >> 6;
    const int lane = tid & 63;
    const int mrow = lane & 15;
    const int kq   = (lane >> 4) * 8;

    const int m0 = blockIdx.x * 128 + wave * 32;
    int r0 = m0 + mrow;      if (r0 > n - 1) r0 = n - 1;
    int r1 = m0 + 16 + mrow; if (r1 > n - 1) r1 = n - 1;

    floatx4 acc[2][NT];
    #pragma unroll
    for (int i = 0; i < 2; ++i)
        #pragma unroll
        for (int j = 0; j < NT; ++j) acc[i][j] = (floatx4){0.f, 0.f, 0.f, 0.f};

    for (int kc = 0; kc < FIN; kc += KC) {
        if (kc) __syncthreads();
        for (int q = tid; q < KC * FOUT; q += 256) {
            int k = q / FOUT, nn = q % FOUT;
            wT[nn * KP + k] = (_Float16)W[(size_t)(kc + k) * FOUT + nn];
        }
        __syncthreads();

        #pragma unroll
        for (int kk = 0; kk < KC; kk += 32) {
            half8 a0, a1;
            if constexpr (sizeof(TA) == 2) {
                const _Float16* xp = (const _Float16*)X;
                a0 = *(const half8*)(xp + (size_t)r0 * FIN + kc + kk + kq);
                a1 = *(const half8*)(xp + (size_t)r1 * FIN + kc + kk + kq);
            } else {
                const float* xp0 = (const float*)X + (size_t)r0 * FIN + kc + kk + kq;
                const float* xp1 = (const float*)X + (size_t)r1 * FIN + kc + kk + kq;
                float4 u0 = *(const float4*)xp0, u1 = *(const float4*)(xp0 + 4);
                float4 v0 = *(const float4*)xp1, v1 = *(const float4*)(xp1 + 4);
                a0 = (half8){(_Float16)u0.x, (_Float16)u0.y, (_Float16)u0.z, (_Float16)u0.w,
                             (_Float16)u1.x, (_Float16)u1.y, (_Float16)u1.z, (_Float16)u1.w};
                a1 = (half8){(_Float16)v0.x, (_Float16)v0.y, (_Float16)v0.z, (_Float16)v0.w,
                             (_Float16)v1.x, (_Float16)v1.y, (_Float16)v1.z, (_Float16)v1.w};
            }
            #pragma unroll
            for (int ct = 0; ct < NT; ++ct) {
                half8 b = *(const half8*)&wT[(ct * 16 + mrow) * KP + kk + kq];
                acc[0][ct] = __builtin_amdgcn_mfma_f32_16x16x32_f16(a0, b, acc[0][ct], 0, 0, 0);
                acc[1][ct] = __builtin_amdgcn_mfma_f32_16x16x32_f16(a1, b, acc[1][ct], 0, 0, 0);
            }
        }
    }

    #pragma unroll
    for (int rt = 0; rt < 2; ++rt) {
        #pragma unroll
        for (int reg = 0; reg < 4; ++reg) {
            int r = m0 + rt * 16 + (lane >> 4) * 4 + reg;
            if (r < n) {
                float s = dinv[r];
                #pragma unroll
                for (int ct = 0; ct < NT; ++ct) {
                    G[(size_t)r * FOUT + ct * 16 + mrow] = (_Float16)(acc[rt][ct][reg] * s);
                }
            }
        }
    }
}

// -------- CSR gather segsum, F=128: half-wave, 4 rows in flight per half --------
template<bool RELU, typename OutT>
__global__ __launch_bounds__(256) void gather128_k(
    const _Float16* __restrict__ g, const int* __restrict__ rowptr,
    const int* __restrict__ eidx, const float* __restrict__ dinv,
    const float* __restrict__ bias, OutT* __restrict__ out, int n)
{
    int wave = threadIdx.x >> 6;
    int lane = threadIdx.x & 63;
    int half = lane >> 5;
    int hl   = lane & 31;
    int node = blockIdx.x * 4 + wave;
    if (node >= n) return;

    int beg = rowptr[node];
    int end = rowptr[node + 1];

    const half4v* g4 = (const half4v*)g;     // row stride = 32 half4
    floatx4 aA = {0.f,0.f,0.f,0.f}, aB = aA, aC = aA, aD = aA;
    if (half == 0) aA = h2f4(g4[(size_t)node * 32 + hl]);   // self loop

    for (int j0 = beg; j0 < end; j0 += 64) {
        int m = end - j0; if (m > 64) m = 64;
        int id = (lane < m) ? eidx[j0 + lane] : 0;
        int t = 0;
        for (; t + 7 < m; t += 8) {
            int i0 = __shfl(id, t + half);
            int i1 = __shfl(id, t + 2 + half);
            int i2 = __shfl(id, t + 4 + half);
            int i3 = __shfl(id, t + 6 + half);
            half4v v0 = g4[(size_t)i0 * 32 + hl];
            half4v v1 = g4[(size_t)i1 * 32 + hl];
            half4v v2 = g4[(size_t)i2 * 32 + hl];
            half4v v3 = g4[(size_t)i3 * 32 + hl];
            aA += h2f4(v0); aB += h2f4(v1); aC += h2f4(v2); aD += h2f4(v3);
        }
        for (; t + 1 < m; t += 2) {
            int i0 = __shfl(id, t + half);
            aA += h2f4(g4[(size_t)i0 * 32 + hl]);
        }
        if (t < m) {
            int i0 = __shfl(id, t);
            if (half == 0) aA += h2f4(g4[(size_t)i0 * 32 + hl]);
        }
    }
    aA += aB; aC += aD; aA += aC;
    aA.x += __shfl_down(aA.x, 32);
    aA.y += __shfl_down(aA.y, 32);
    aA.z += __shfl_down(aA.z, 32);
    aA.w += __shfl_down(aA.w, 32);

    if (half == 0) {
        float sc = dinv[node];
        float4 bb = *(const float4*)(bias + 4 * hl);
        float o0 = fmaf(aA.x, sc, bb.x);
        float o1 = fmaf(aA.y, sc, bb.y);
        float o2 = fmaf(aA.z, sc, bb.z);
        float o3 = fmaf(aA.w, sc, bb.w);
        if (RELU) {
            o0 = fmaxf(o0, 0.f); o1 = fmaxf(o1, 0.f);
            o2 = fmaxf(o2, 0.f); o3 = fmaxf(o3, 0.f);
        }
        if constexpr (sizeof(OutT) == 2) {
            ((half4v*)out)[(size_t)node * 32 + hl] =
                (half4v){(_Float16)o0, (_Float16)o1, (_Float16)o2, (_Float16)o3};
        } else {
            *(float4*)((float*)out + (size_t)node * 128 + 4 * hl) =
                make_float4(o0, o1, o2, o3);
        }
    }
}

// -------- F=64 variant: half-wave, half2 loads, 4 rows in flight per half --------
template<bool RELU>
__global__ __launch_bounds__(256) void gather64_k(
    const _Float16* __restrict__ g, const int* __restrict__ rowptr,
    const int* __restrict__ eidx, const float* __restrict__ dinv,
    const float* __restrict__ bias, float* __restrict__ out, int n)
{
    int wave = threadIdx.x >> 6;
    int lane = threadIdx.x & 63;
    int half = lane >> 5;
    int hl   = lane & 31;
    int node = blockIdx.x * 4 + wave;
    if (node >= n) return;

    int beg = rowptr[node];
    int end = rowptr[node + 1];

    const half2v* g2 = (const half2v*)g;     // row stride = 32 half2
    float ax=0.f, ay=0.f, bx=0.f, by=0.f, cx=0.f, cy=0.f, dx=0.f, dy=0.f;
    if (half == 0) {
        half2v v = g2[(size_t)node * 32 + hl];
        ax = (float)v.x; ay = (float)v.y;
    }

    for (int j0 = beg; j0 < end; j0 += 64) {
        int m = end - j0; if (m > 64) m = 64;
        int id = (lane < m) ? eidx[j0 + lane] : 0;
        int t = 0;
        for (; t + 7 < m; t += 8) {
            int i0 = __shfl(id, t + half);
            int i1 = __shfl(id, t + 2 + half);
            int i2 = __shfl(id, t + 4 + half);
            int i3 = __shfl(id, t + 6 + half);
            half2v v0 = g2[(size_t)i0 * 32 + hl];
            half2v v1 = g2[(size_t)i1 * 32 + hl];
            half2v v2 = g2[(size_t)i2 * 32 + hl];
            half2v v3 = g2[(size_t)i3 * 32 + hl];
            ax += (float)v0.x; ay += (float)v0.y;
            bx += (float)v1.x; by += (float)v1.y;
            cx += (float)v2.x; cy += (float)v2.y;
            dx += (float)v3.x; dy += (float)v3.y;
        }
        for (; t + 1 < m; t += 2) {
            int i0 = __shfl(id, t + half);
            half2v v0 = g2[(size_t)i0 * 32 + hl];
            ax += (float)v0.x; ay += (float)v0.y;
        }
        if (t < m) {
            int i0 = __shfl(id, t);
            if (half == 0) {
                half2v v0 = g2[(size_t)i0 * 32 + hl];
                ax += (float)v0.x; ay += (float)v0.y;
            }
        }
    }
    ax += bx + cx + dx; ay += by + cy + dy;
    ax += __shfl_down(ax, 32);
    ay += __shfl_down(ay, 32);

    if (half == 0) {
        float sc = dinv[node];
        float2 bb = *(const float2*)(bias + 2 * hl);
        float ox = fmaf(ax, sc, bb.x);
        float oy = fmaf(ay, sc, bb.y);
        if (RELU) { ox = fmaxf(ox, 0.f); oy = fmaxf(oy, 0.f); }
        *(float2*)(out + (size_t)node * 64 + 2 * hl) = make_float2(ox, oy);
    }
}

extern "C" void kernel_launch(void* const* d_in, const int* in_sizes, int n_in,
                              void* d_out, int out_size, void* d_ws, size_t ws_size,
                              hipStream_t stream) {
    const float* x  = (const float*)d_in[0];
    const int*   ei = (const int*)d_in[1];     // [2, E] int32
    const float* W1 = (const float*)d_in[2];
    const float* b1 = (const float*)d_in[3];
    const float* W2 = (const float*)d_in[4];
    const float* b2 = (const float*)d_in[5];
    const float* W3 = (const float*)d_in[6];
    const float* b3 = (const float*)d_in[7];
    float* out = (float*)d_out;

    const int N = NNODES;
    const int E = in_sizes[1] / 2;
    const int* srcI = ei;
    const int* dstI = ei + E;

    const int npb = (E + PB - 1) / PB;

    char* ws = (char*)d_ws;
    size_t p = 0;
    auto alloc = [&](size_t bytes) { void* r = ws + p; p = (p + bytes + 255) & ~(size_t)255; return r; };
    float*     dinv   = (float*)    alloc((size_t)N * 4);
    int*       rowptr = (int*)      alloc((size_t)(N + 1) * 4);
    int*       bbase  = (int*)      alloc((size_t)(NB + 1) * 4);
    int*       T      = (int*)      alloc((size_t)NB * 4);
    int*       H      = (int*)      alloc((size_t)npb * NB * 4);
    int*       O      = (int*)      alloc((size_t)npb * NB * 4);
    unsigned*  binned = (unsigned*) alloc((size_t)E * 4);
    int*       eidx   = (int*)      alloc((size_t)E * 4);
    _Float16*  A      = (_Float16*) alloc((size_t)N * 128 * 2);
    _Float16*  Ch     = (_Float16*) alloc((size_t)N * 128 * 2);

    const int nb_node4 = (N + 3) / 4;
    const int nb_gemm = (N + 127) / 128;

    // ---- CSR build: deterministic partition + per-bucket LDS sort ----
    blockhist_k<<<npb, 256, 0, stream>>>(dstI, H, E);
    bucketscan_k<<<NB, 256, 0, stream>>>(H, O, T, npb);
    scanT_k<<<1, 512, 0, stream>>>(T, bbase, E);
    scatter_k<<<npb, 256, 0, stream>>>(srcI, dstI, O, bbase, binned, E);
    bucket_fill_k<<<NB, 256, 0, stream>>>(binned, bbase, rowptr, eidx, dinv, N, E);

    // ---- layer 1: FEAT=256 -> HID=128 ----
    gemm_mfma_k<float, 256, 128><<<nb_gemm, 256, 0, stream>>>(x, W1, dinv, A, N);
    gather128_k<true, _Float16><<<nb_node4, 256, 0, stream>>>(A, rowptr, eidx, dinv, b1, Ch, N);

    // ---- layer 2: HID=128 -> HID=128 ----
    gemm_mfma_k<_Float16, 128, 128><<<nb_gemm, 256, 0, stream>>>(Ch, W2, dinv, A, N);
    gather128_k<true, _Float16><<<nb_node4, 256, 0, stream>>>(A, rowptr, eidx, dinv, b2, Ch, N);

    // ---- layer 3: HID=128 -> OUT=64 ----
    gemm_mfma_k<_Float16, 128, 64><<<nb_gemm, 256, 0, stream>>>(Ch, W3, dinv, A, N);
    gather64_k<false><<<nb_node4, 256, 0, stream>>>(A, rowptr, eidx, dinv, b3, out, N);
}